// Round 15
// baseline (366.519 us; speedup 1.0000x reference)
//
#include <hip/hip_runtime.h>
#include <stdint.h>

// ---------- bf16 helpers (storage = unsigned short) ----------
__device__ __forceinline__ float b2f(unsigned short u) {
    union { uint32_t i; float f; } v; v.i = ((uint32_t)u) << 16; return v.f;
}
__device__ __forceinline__ unsigned short f2b(float f) {
    union { float f; uint32_t i; } v; v.f = f;
    uint32_t r = v.i + 0x7fffu + ((v.i >> 16) & 1u);   // RNE
    return (unsigned short)(r >> 16);
}

typedef __bf16 bf16x8 __attribute__((ext_vector_type(8)));
typedef float  f32x16 __attribute__((ext_vector_type(16)));

// ---------------------------------------------------------------------------
// Fused per-layer W builder (device fn). Block owns one (n2,m2) pair:
//   stage A: T-slice[r1][n3][m3] (2048 f32, LDS) = sum_r2 c1[r1,n2,m2,r2]*c2[r2,n3,m3]
//   stage B: W[(m1,m2,m3)][(n1,n2,n3)] = sum_r1 c0[n1,m1,r1]*Tslice[r1][n3][m3]
// W layout (R3-validated): row-major [M][K], M=(m1,m2,m3), K=(n1,n2,n3).
// ---------------------------------------------------------------------------
template<int N1, int N2, int N3, int M1, int M2, int M3>
__device__ __forceinline__ void build_layer(int b, int tid,
                                            const float* __restrict__ c0,
                                            const float* __restrict__ c1,
                                            const float* __restrict__ c2,
                                            unsigned short* __restrict__ W,
                                            float* Ts) {
    constexpr int K = N1 * N2 * N3;
    const int n2 = b / M2;
    const int m2 = b % M2;

    // stage A: 2048 elems, 8/thread, coalesced over c2/Ts
#pragma unroll
    for (int e = 0; e < 8; ++e) {
        const int idx = e * 256 + tid;                 // m3 fastest
        const int m3 = idx % M3;
        const int n3 = (idx / M3) % N3;
        const int r1 = idx / (M3 * N3);
        float s = 0.f;
#pragma unroll
        for (int r2 = 0; r2 < 16; ++r2)
            s += c1[((r1 * N2 + n2) * M2 + m2) * 16 + r2] *
                 c2[(r2 * N3 + n3) * M3 + m3];
        Ts[idx] = s;
    }
    __syncthreads();

    // stage B: M1*M3*N1*N3 = 16384 elems, 64/thread
    constexpr int C   = M1 * M3;        // (m1,m3) combos
    constexpr int P   = 256 / C;        // threads sharing a combo
    constexpr int NCH = N1 / P;         // n1 values per thread
    const int combo  = tid % C;
    const int m1     = combo / M3;
    const int m3     = combo % M3;
    const int n1base = (tid / C) * NCH;

#pragma unroll
    for (int ni = 0; ni < NCH; ++ni) {
        const int n1 = n1base + ni;
        float acc[N3] = {};
#pragma unroll
        for (int r1 = 0; r1 < 16; ++r1) {
            const float c0v = c0[(n1 * M1 + m1) * 16 + r1];
#pragma unroll
            for (int n3 = 0; n3 < N3; ++n3)
                acc[n3] += c0v * Ts[(r1 * N3 + n3) * M3 + m3];
        }
        unsigned short ob[N3];
#pragma unroll
        for (int n3 = 0; n3 < N3; ++n3) ob[n3] = f2b(acc[n3]);
        unsigned short* dst = W + (size_t)((m1 * M2 + m2) * M3 + m3) * K
                                + (n1 * N2 + n2) * N3;
#pragma unroll
        for (int c = 0; c < N3 / 8; ++c)
            ((int4*)dst)[c] = ((const int4*)ob)[c];
    }
}

// WHICH: 0 = both layers (512 blocks), 1 = layer1 only, 2 = layer2 only (256)
template<int WHICH>
__global__ __launch_bounds__(256)
void prep(const float* __restrict__ f1c0, const float* __restrict__ f1c1,
          const float* __restrict__ f1c2,
          const float* __restrict__ f2c0, const float* __restrict__ f2c1,
          const float* __restrict__ f2c2,
          unsigned short* __restrict__ W1, unsigned short* __restrict__ W2) {
    __shared__ float Ts[2048];
    const int tid = threadIdx.x;
    if (WHICH == 1 || (WHICH == 0 && blockIdx.x < 256)) {
        // layer 1: in (8,16,8) -> out (16,16,16)
        build_layer<8, 16, 8, 16, 16, 16>(blockIdx.x & 255, tid,
                                          f1c0, f1c1, f1c2, W1, Ts);
    } else {
        // layer 2: in (16,16,16) -> out (8,16,8)
        build_layer<16, 16, 16, 8, 16, 8>(blockIdx.x & 255, tid,
                                          f2c0, f2c1, f2c2, W2, Ts);
    }
}

// ---------------------------------------------------------------------------
// GEMM (32x32x16 MFMA, all-waves, tall wave tile) — R14 config, unchanged.
// Block BM x BN, 4 waves (2x2), wave tile (BM/2)x(BN/2) = FIxFJ 32x32 frags.
// NSUB 64-wide K-subtiles per barrier. Swizzle (R13-verified, 0 conflicts).
// Register staging only (global_load_lds corrupts at >4 blocks/CU — R7/R8).
// C/D mapping (m74/m101): col=lane&31, row=(reg&3)+8*(reg>>2)+4*(lane>>5).
// ---------------------------------------------------------------------------
template<int BM, int BN, int NSUB, int KTOT, bool DO_GELU, bool A_F32, bool C_F32>
__global__ __launch_bounds__(256, 2)
void gemm32v2(const void* __restrict__ Av,
              const unsigned short* __restrict__ Bt,
              const float* __restrict__ bias,
              void* __restrict__ Cv,
              int Ncols) {
    constexpr int FI  = BM / 64;
    constexpr int FJ  = BN / 64;
    constexpr int ASZ = BM * 64;
    constexpr int BSZ = BN * 64;
    constexpr int PA  = BM / 32;
    constexpr int PB  = BN / 32;
    __shared__ unsigned short As[NSUB * ASZ];
    __shared__ unsigned short Bs[NSUB * BSZ];

    const int tid  = threadIdx.x;
    const int lane = tid & 63;
    const int wave = tid >> 6;
    const int rowBase = blockIdx.y * BM;
    const int colBase = blockIdx.x * BN;

    const int waveM = (wave >> 1) * (BM / 2);
    const int waveN = (wave & 1) * (BN / 2);

    f32x16 acc[FI][FJ] = {};

    const int lr    = lane >> 3;
    const int jj    = lane & 7;
    const int m32   = lane & 31;
    const int khalf = lane >> 5;

    for (int k0 = 0; k0 < KTOT; k0 += NSUB * 64) {
#pragma unroll
        for (int s = 0; s < NSUB; ++s) {
            const int kk = k0 + s * 64;
#pragma unroll
            for (int it = 0; it < PA; ++it) {
                const int c  = wave * PA + it;
                const int jg = jj ^ lr ^ (c & 7);
                const size_t aoff = (size_t)(rowBase + c * 8 + lr) * KTOT + kk + jg * 8;
                int4 v;
                if (A_F32) {
                    const float* ga = (const float*)Av + aoff;
                    float4 f0 = *(const float4*)ga;
                    float4 f1 = *(const float4*)(ga + 4);
                    v.x = (uint32_t)f2b(f0.x) | ((uint32_t)f2b(f0.y) << 16);
                    v.y = (uint32_t)f2b(f0.z) | ((uint32_t)f2b(f0.w) << 16);
                    v.z = (uint32_t)f2b(f1.x) | ((uint32_t)f2b(f1.y) << 16);
                    v.w = (uint32_t)f2b(f1.z) | ((uint32_t)f2b(f1.w) << 16);
                } else {
                    v = *(const int4*)((const unsigned short*)Av + aoff);
                }
                *(int4*)&As[s * ASZ + c * 512 + lane * 8] = v;
            }
#pragma unroll
            for (int it = 0; it < PB; ++it) {
                const int c  = wave * PB + it;
                const int jg = jj ^ lr ^ (c & 7);
                *(int4*)&Bs[s * BSZ + c * 512 + lane * 8] =
                    *(const int4*)(Bt + (size_t)(colBase + c * 8 + lr) * KTOT + kk + jg * 8);
            }
        }
        __syncthreads();

#pragma unroll
        for (int s = 0; s < NSUB; ++s) {
#pragma unroll
            for (int ks = 0; ks < 4; ++ks) {
                bf16x8 a_f[FI], b_f[FJ];
#pragma unroll
                for (int i = 0; i < FI; ++i) {
                    const int key  = (m32 & 7) ^
                        ((((waveM >> 3) + 4 * i) + (m32 >> 3)) & 7);
                    const int slot = ((ks * 2 + khalf) ^ key) * 8;
                    a_f[i] = *(const bf16x8*)&As[s * ASZ +
                              (waveM + i * 32 + m32) * 64 + slot];
                }
#pragma unroll
                for (int j = 0; j < FJ; ++j) {
                    const int key  = (m32 & 7) ^
                        ((((waveN >> 3) + 4 * j) + (m32 >> 3)) & 7);
                    const int slot = ((ks * 2 + khalf) ^ key) * 8;
                    b_f[j] = *(const bf16x8*)&Bs[s * BSZ +
                              (waveN + j * 32 + m32) * 64 + slot];
                }
#pragma unroll
                for (int i = 0; i < FI; ++i)
#pragma unroll
                    for (int j = 0; j < FJ; ++j)
                        acc[i][j] = __builtin_amdgcn_mfma_f32_32x32x16_bf16(
                            a_f[i], b_f[j], acc[i][j], 0, 0, 0);
            }
        }
        __syncthreads();
    }

    // Epilogue
#pragma unroll
    for (int i = 0; i < FI; ++i) {
#pragma unroll
        for (int j = 0; j < FJ; ++j) {
            const int col = colBase + waveN + j * 32 + m32;
            const float bv = bias[col];
#pragma unroll
            for (int reg = 0; reg < 16; ++reg) {
                const int row = rowBase + waveM + i * 32 +
                                (reg & 3) + 8 * (reg >> 2) + 4 * khalf;
                float z = acc[i][j][reg] + bv;
                if (DO_GELU)
                    z = 0.5f * z * (1.f + erff(z * 0.70710678118654752f));
                const size_t off = (size_t)row * Ncols + col;
                if (C_F32) ((float*)Cv)[off] = z;
                else       ((unsigned short*)Cv)[off] = f2b(z);
            }
        }
    }
}

// ---------------------------------------------------------------------------
extern "C" void kernel_launch(void* const* d_in, const int* in_sizes, int n_in,
                              void* d_out, int out_size, void* d_ws, size_t ws_size,
                              hipStream_t stream) {
    const float* x      = (const float*)d_in[0];   // [4096,1024] fp32
    const float* fc1_c0 = (const float*)d_in[1];
    const float* fc1_c1 = (const float*)d_in[2];
    const float* fc1_c2 = (const float*)d_in[3];
    const float* fc1_b  = (const float*)d_in[4];
    const float* fc2_c0 = (const float*)d_in[5];
    const float* fc2_c1 = (const float*)d_in[6];
    const float* fc2_c2 = (const float*)d_in[7];
    const float* fc2_b  = (const float*)d_in[8];

    char* ws = (char*)d_ws;
    const bool big = ws_size >= (48ull << 20);

    if (big) {
        // 48 MB layout: W1 [0,8M), W2 [8,16M), h [16,48M). 3 dispatches.
        unsigned short* W1 = (unsigned short*)(ws);
        unsigned short* W2 = (unsigned short*)(ws + (8u << 20));
        unsigned short* h  = (unsigned short*)(ws + (16u << 20));

        prep<0><<<512, 256, 0, stream>>>(fc1_c0, fc1_c1, fc1_c2,
                                         fc2_c0, fc2_c1, fc2_c2, W1, W2);
        gemm32v2<256, 128, 1, 1024, true, true, false>
            <<<dim3(32, 16), 256, 0, stream>>>(x, W1, fc1_b, h, 4096);
        gemm32v2<64, 128, 2, 4096, false, false, true>
            <<<dim3(8, 64), 256, 0, stream>>>(h, W2, fc2_b, d_out, 1024);
    } else {
        // 40 MB layout: W [0,8M) shared, h [8,40M). 4 dispatches.
        unsigned short* W = (unsigned short*)(ws);
        unsigned short* h = (unsigned short*)(ws + (8u << 20));

        prep<1><<<256, 256, 0, stream>>>(fc1_c0, fc1_c1, fc1_c2,
                                         fc2_c0, fc2_c1, fc2_c2, W, W);
        gemm32v2<256, 128, 1, 1024, true, true, false>
            <<<dim3(32, 16), 256, 0, stream>>>(x, W, fc1_b, h, 4096);
        prep<2><<<256, 256, 0, stream>>>(fc1_c0, fc1_c1, fc1_c2,
                                         fc2_c0, fc2_c1, fc2_c2, W, W);
        gemm32v2<64, 128, 2, 4096, false, false, true>
            <<<dim3(8, 64), 256, 0, stream>>>(h, W, fc2_b, d_out, 1024);
    }
}